// Round 2
// baseline (528.470 us; speedup 1.0000x reference)
//
#include <hip/hip_runtime.h>
#include <hip/hip_bf16.h>
#include <stdint.h>
#include <stddef.h>

using bf16 = __bf16;
typedef __attribute__((ext_vector_type(8))) __bf16 bf16x8;
typedef __attribute__((ext_vector_type(4))) float f32x4;

// ---------------------------------------------------------------------------
__device__ __forceinline__ void async_copy16(const bf16* g, bf16* l) {
    __builtin_amdgcn_global_load_lds(
        (const __attribute__((address_space(1))) void*)g,
        (__attribute__((address_space(3))) void*)l, 16, 0, 0);
}

// ---------------------------------------------------------------------------
// Transpose in[R][C] fp32 -> out[C][R]: optional fp32 copy, bf16 hi, bf16 lo
// (lo = bf16(v - float(hi)) -> split-precision storage).
__global__ __launch_bounds__(256)
void transpose_f(const float* __restrict__ in, float* __restrict__ outF,
                 bf16* __restrict__ outHi, bf16* __restrict__ outLo,
                 int R, int C) {
    __shared__ float tile[32][33];
    const int tx = threadIdx.x & 31, ty = threadIdx.x >> 5;  // 32 x 8
    const int c0 = blockIdx.x * 32, r0 = blockIdx.y * 32;
#pragma unroll
    for (int j = 0; j < 4; j++)
        tile[ty + j * 8][tx] = in[(size_t)(r0 + ty + j * 8) * C + c0 + tx];
    __syncthreads();
#pragma unroll
    for (int j = 0; j < 4; j++) {
        float v = tile[tx][ty + j * 8];
        size_t idx = (size_t)(c0 + ty + j * 8) * R + r0 + tx;
        if (outF) outF[idx] = v;
        bf16 hi = (bf16)v;
        outHi[idx] = hi;
        if (outLo) outLo[idx] = (bf16)(v - (float)hi);
    }
}

// ---------------------------------------------------------------------------
// Causal softmax, IN-PLACE: reads fp32 row S[row][0..N), writes bf16 A into
// the same memory (row base reinterpreted as bf16*, so A row pitch = 2N bf16
// elements). All loads complete before any stores (barrier-ordered).
// Zeros written for cols > row.
__global__ __launch_bounds__(256)
void softmax_causal_inplace(float* __restrict__ S, int N) {
    const int row = blockIdx.x;
    const int len = row + 1;
    float* s = S + (size_t)row * N;
    bf16* a = (bf16*)s;
    __shared__ float red[256];
    const int t = threadIdx.x;

    float v[16];  // N=4096 / 256 threads
#pragma unroll
    for (int j = 0; j < 16; j++) v[j] = s[t + j * 256];

    float mx = -1e30f;
#pragma unroll
    for (int j = 0; j < 16; j++) {
        int c = t + j * 256;
        if (c < len) mx = fmaxf(mx, v[j]);
    }
    red[t] = mx; __syncthreads();
    for (int o = 128; o > 0; o >>= 1) { if (t < o) red[t] = fmaxf(red[t], red[t + o]); __syncthreads(); }
    mx = red[0]; __syncthreads();

    float sum = 0.f;
#pragma unroll
    for (int j = 0; j < 16; j++) {
        int c = t + j * 256;
        if (c < len) sum += __expf(v[j] - mx);
    }
    red[t] = sum; __syncthreads();
    for (int o = 128; o > 0; o >>= 1) { if (t < o) red[t] += red[t + o]; __syncthreads(); }
    const float inv = 1.0f / red[0];
    // All loads done (barrier above); safe to overwrite.
#pragma unroll
    for (int j = 0; j < 16; j++) {
        int c = t + j * 256;
        a[c] = (bf16)((c < len) ? __expf(v[j] - mx) * inv : 0.0f);
    }
}

// ---------------------------------------------------------------------------
// C[M,N] = A[M,K] * B[N,K]^T, bf16 MFMA, 128x128x32, 256 threads (m97-style).
// lda = element stride between A rows (B stride is K).
// MODE 0: Cb = bf16(acc)
// MODE 2: Cf = acc + resid; Cb = bf16(Cf)
// MODE 3: Cb = bf16(relu(acc))
// MODE 4: Cf[col*M + row] = acc + resid[row*N + col]   (transposed store)
constexpr int BM = 128, BN = 128, BK = 32;

template <int MODE, bool CAUSAL_K>
__global__ __launch_bounds__(256)
void gemm_bt(const bf16* __restrict__ A, const bf16* __restrict__ B,
             float* __restrict__ Cf, bf16* __restrict__ Cb,
             const float* __restrict__ resid, int M, int N, int K, int lda) {
    const int m0 = blockIdx.y * BM, n0 = blockIdx.x * BN;

    __shared__ alignas(16) bf16 lA[BM * BK];
    __shared__ alignas(16) bf16 lB[BN * BK];

    const int t = threadIdx.x;
    const int lane = t & 63, wave = t >> 6;
    const int wm = (wave >> 1) * 64, wn = (wave & 1) * 64;
    const int lm = lane & 15, lq = lane >> 4;
    const int sr = t >> 2, sk = (t & 3) * 8;

    const int Keff = CAUSAL_K ? (K < m0 + BM ? K : m0 + BM) : K;

    const bf16* ga = A + (size_t)(m0 + sr) * lda + sk;
    const bf16* gb = B + (size_t)(n0 + sr) * K + sk;
    bf16* la = &lA[t * 8];
    bf16* lb = &lB[t * 8];

    f32x4 acc[4][4] = {};

    for (int k0 = 0; k0 < Keff; k0 += BK) {
        async_copy16(ga + k0, la);
        async_copy16(ga + k0 + (size_t)64 * lda, la + 64 * BK);
        async_copy16(gb + k0, lb);
        async_copy16(gb + k0 + (size_t)64 * K, lb + 64 * BK);
        __syncthreads();

        bf16x8 af[4], bfr[4];
#pragma unroll
        for (int i = 0; i < 4; i++)
            af[i] = *(const bf16x8*)&lA[(wm + i * 16 + lm) * BK + lq * 8];
#pragma unroll
        for (int i = 0; i < 4; i++)
            bfr[i] = *(const bf16x8*)&lB[(wn + i * 16 + lm) * BK + lq * 8];
#pragma unroll
        for (int i = 0; i < 4; i++)
#pragma unroll
            for (int j = 0; j < 4; j++)
                acc[i][j] = __builtin_amdgcn_mfma_f32_16x16x32_bf16(
                    af[i], bfr[j], acc[i][j], 0, 0, 0);
        __syncthreads();
    }

    // C/D layout: col = lane&15, row = (lane>>4)*4 + reg.
#pragma unroll
    for (int i = 0; i < 4; i++) {
        const int row = m0 + wm + i * 16 + lq * 4;
#pragma unroll
        for (int j = 0; j < 4; j++) {
            const int col = n0 + wn + j * 16 + lm;
            f32x4 v = acc[i][j];
            if (MODE == 0) {
#pragma unroll
                for (int r = 0; r < 4; r++)
                    Cb[(size_t)(row + r) * N + col] = (bf16)v[r];
            } else if (MODE == 2) {
#pragma unroll
                for (int r = 0; r < 4; r++) {
                    float o = v[r] + resid[(size_t)(row + r) * N + col];
                    Cf[(size_t)(row + r) * N + col] = o;
                    Cb[(size_t)(row + r) * N + col] = (bf16)o;
                }
            } else if (MODE == 3) {
#pragma unroll
                for (int r = 0; r < 4; r++)
                    Cb[(size_t)(row + r) * N + col] = (bf16)fmaxf(v[r], 0.0f);
            } else {
#pragma unroll
                for (int r = 0; r < 4; r++) {
                    float o = v[r] + resid[(size_t)(row + r) * N + col];
                    Cf[(size_t)col * M + (row + r)] = o;
                }
            }
        }
    }
}

// ---------------------------------------------------------------------------
// Split-precision GEMM: C = (Ahi+Alo) * (Bhi+Blo)^T, 3 MFMA passes
// (hi*hi + hi*lo + lo*hi), fp32 accumulate -> near-fp32 result.
// MODE 1: Cf = acc  (+SKIP_UPPER for causal scores)
// MODE 5: Chi = bf16(acc); Clo = bf16(acc - Chi)
template <int MODE, bool SKIP_UPPER>
__global__ __launch_bounds__(256)
void gemm_bt_split(const bf16* __restrict__ Ahi, const bf16* __restrict__ Alo,
                   const bf16* __restrict__ Bhi, const bf16* __restrict__ Blo,
                   float* __restrict__ Cf, bf16* __restrict__ Chi,
                   bf16* __restrict__ Clo, int M, int N, int K) {
    const int m0 = blockIdx.y * BM, n0 = blockIdx.x * BN;
    if (SKIP_UPPER && n0 > m0) return;

    __shared__ alignas(16) bf16 lAh[BM * BK], lAl[BM * BK];
    __shared__ alignas(16) bf16 lBh[BN * BK], lBl[BN * BK];

    const int t = threadIdx.x;
    const int lane = t & 63, wave = t >> 6;
    const int wm = (wave >> 1) * 64, wn = (wave & 1) * 64;
    const int lm = lane & 15, lq = lane >> 4;
    const int sr = t >> 2, sk = (t & 3) * 8;

    const size_t go = (size_t)(m0 + sr) * K + sk;
    const size_t gBo = (size_t)(n0 + sr) * K + sk;

    f32x4 acc[4][4] = {};

    for (int k0 = 0; k0 < K; k0 += BK) {
        async_copy16(Ahi + go + k0, &lAh[t * 8]);
        async_copy16(Ahi + go + k0 + (size_t)64 * K, &lAh[t * 8 + 64 * BK]);
        async_copy16(Alo + go + k0, &lAl[t * 8]);
        async_copy16(Alo + go + k0 + (size_t)64 * K, &lAl[t * 8 + 64 * BK]);
        async_copy16(Bhi + gBo + k0, &lBh[t * 8]);
        async_copy16(Bhi + gBo + k0 + (size_t)64 * K, &lBh[t * 8 + 64 * BK]);
        async_copy16(Blo + gBo + k0, &lBl[t * 8]);
        async_copy16(Blo + gBo + k0 + (size_t)64 * K, &lBl[t * 8 + 64 * BK]);
        __syncthreads();

        bf16x8 ah[4], al[4], bh[4], bl[4];
#pragma unroll
        for (int i = 0; i < 4; i++) {
            const int ro = (wm + i * 16 + lm) * BK + lq * 8;
            ah[i] = *(const bf16x8*)&lAh[ro];
            al[i] = *(const bf16x8*)&lAl[ro];
        }
#pragma unroll
        for (int j = 0; j < 4; j++) {
            const int ro = (wn + j * 16 + lm) * BK + lq * 8;
            bh[j] = *(const bf16x8*)&lBh[ro];
            bl[j] = *(const bf16x8*)&lBl[ro];
        }
#pragma unroll
        for (int i = 0; i < 4; i++)
#pragma unroll
            for (int j = 0; j < 4; j++) {
                acc[i][j] = __builtin_amdgcn_mfma_f32_16x16x32_bf16(ah[i], bh[j], acc[i][j], 0, 0, 0);
                acc[i][j] = __builtin_amdgcn_mfma_f32_16x16x32_bf16(ah[i], bl[j], acc[i][j], 0, 0, 0);
                acc[i][j] = __builtin_amdgcn_mfma_f32_16x16x32_bf16(al[i], bh[j], acc[i][j], 0, 0, 0);
            }
        __syncthreads();
    }

#pragma unroll
    for (int i = 0; i < 4; i++) {
        const int row = m0 + wm + i * 16 + lq * 4;
#pragma unroll
        for (int j = 0; j < 4; j++) {
            const int col = n0 + wn + j * 16 + lm;
            f32x4 v = acc[i][j];
            if (MODE == 1) {
#pragma unroll
                for (int r = 0; r < 4; r++)
                    Cf[(size_t)(row + r) * N + col] = v[r];
            } else {
#pragma unroll
                for (int r = 0; r < 4; r++) {
                    float f = v[r];
                    bf16 hi = (bf16)f;
                    Chi[(size_t)(row + r) * N + col] = hi;
                    Clo[(size_t)(row + r) * N + col] = (bf16)(f - (float)hi);
                }
            }
        }
    }
}

// ---------------------------------------------------------------------------
extern "C" void kernel_launch(void* const* d_in, const int* in_sizes, int n_in,
                              void* d_out, int out_size, void* d_ws, size_t ws_size,
                              hipStream_t stream) {
    const int D = 1024, NT = 4096;
    const float* X = (const float*)d_in[0];
    const float* W[6] = {(const float*)d_in[1], (const float*)d_in[2],
                         (const float*)d_in[3], (const float*)d_in[4],
                         (const float*)d_in[5], (const float*)d_in[6]};
    char* ws = (char*)d_ws;
    auto MB = [](size_t x) { return x << 20; };

    // Workspace layout, 144 MB total with lifetime-based reuse:
    float* Xtf   = (float*)(ws + MB(0));    // [NT][D] fp32, exact residual
    bf16*  Xhi   = (bf16*)(ws + MB(16));    // [NT][D]   (dead after V proj)
    bf16*  Wh[6];
    for (int i = 0; i < 6; i++) Wh[i] = (bf16*)(ws + MB(24 + 2 * i));  // hi, K-major
    bf16*  Qhi   = (bf16*)(ws + MB(36));    // [NT][D]   (dead after scores)
    bf16*  Khi   = (bf16*)(ws + MB(44));    // [NT][D]   (dead after scores)
    bf16*  Xlo   = (bf16*)(ws + MB(52));    // [NT][D]   (dead after Q,K proj)
    bf16*  Wqlo  = (bf16*)(ws + MB(60));    // [D][D]
    bf16*  Wklo  = (bf16*)(ws + MB(62));    // [D][D]
    bf16*  Qlo   = (bf16*)(ws + MB(64));    // [NT][D]   (dead after scores)
    bf16*  Klo   = (bf16*)(ws + MB(72));    // [NT][D]   (dead after scores)
    float* S     = (float*)(ws + MB(80));   // [NT][NT] fp32; A bf16 in-place after softmax
    // Reuse (after the region's previous tenant is dead):
    bf16*  Vb    = (bf16*)(ws + MB(64));    // over Qlo
    bf16*  RHt   = (bf16*)(ws + MB(72));    // over Klo  [D][NT]
    float* Y1f   = (float*)(ws + MB(36));   // over Qhi+Khi [NT][D]
    bf16*  Y1b   = (bf16*)(ws + MB(52));    // over Xlo
    bf16*  hb    = (bf16*)(ws + MB(16));    // over Xhi
    float* outF  = (float*)d_out;           // [D][NT]

    // 1. Transposes + split conversion.
    transpose_f<<<dim3(NT / 32, D / 32), 256, 0, stream>>>(X, Xtf, Xhi, Xlo, D, NT);
    transpose_f<<<dim3(D / 32, D / 32), 256, 0, stream>>>(W[0], nullptr, Wh[0], Wqlo, D, D);
    transpose_f<<<dim3(D / 32, D / 32), 256, 0, stream>>>(W[1], nullptr, Wh[1], Wklo, D, D);
    for (int i = 2; i < 6; i++)
        transpose_f<<<dim3(D / 32, D / 32), 256, 0, stream>>>(W[i], nullptr, Wh[i], nullptr, D, D);

    // 2. Q, K projections (split precision in, split out).
    gemm_bt_split<5, false><<<dim3(D / BN, NT / BM), 256, 0, stream>>>(
        Xhi, Xlo, Wh[0], Wqlo, nullptr, Qhi, Qlo, NT, D, D);
    gemm_bt_split<5, false><<<dim3(D / BN, NT / BM), 256, 0, stream>>>(
        Xhi, Xlo, Wh[1], Wklo, nullptr, Khi, Klo, NT, D, D);

    // 3. Scores S = Q K^T (split, fp32 out, skip fully-masked upper blocks).
    gemm_bt_split<1, true><<<dim3(NT / BN, NT / BM), 256, 0, stream>>>(
        Qhi, Qlo, Khi, Klo, S, nullptr, nullptr, NT, NT, D);

    // 4. Softmax in-place (S fp32 -> A bf16, row pitch 2*NT bf16 elems).
    softmax_causal_inplace<<<NT, 256, 0, stream>>>(S, NT);
    bf16* Ab = (bf16*)S;  // lda = 2*NT

    // 5. V projection, then RH^T = Wo_t * V^T (plain bf16). Vb/RHt reuse
    //    Qlo/Klo which are dead after step 3.
    gemm_bt<0, false><<<dim3(D / BN, NT / BM), 256, 0, stream>>>(
        Xhi, Wh[2], nullptr, Vb, nullptr, NT, D, D, D);
    gemm_bt<0, false><<<dim3(NT / BN, D / BM), 256, 0, stream>>>(
        Wh[3], Vb, nullptr, RHt, nullptr, D, NT, D, D);

    // 6. Y1 = Xt + A @ RH (causal-K truncation; fp32 + bf16 out).
    gemm_bt<2, true><<<dim3(D / BN, NT / BM), 256, 0, stream>>>(
        Ab, RHt, Y1f, Y1b, Xtf, NT, D, NT, 2 * NT);

    // 7. h = relu(Y1 @ mlp_in).
    gemm_bt<3, false><<<dim3(D / BN, NT / BM), 256, 0, stream>>>(
        Y1b, Wh[4], nullptr, hb, nullptr, NT, D, D, D);

    // 8. out = (Y1 + h @ mlp_out)^T.
    gemm_bt<4, false><<<dim3(D / BN, NT / BM), 256, 0, stream>>>(
        hb, Wh[5], outF, nullptr, Y1f, NT, D, D, D);
}

// Round 3
// 442.203 us; speedup vs baseline: 1.1951x; 1.1951x over previous
//
#include <hip/hip_runtime.h>
#include <hip/hip_bf16.h>
#include <stdint.h>
#include <stddef.h>

using bf16 = __bf16;
typedef __attribute__((ext_vector_type(8))) __bf16 bf16x8;
typedef __attribute__((ext_vector_type(4))) float f32x4;

constexpr int BM = 128, BN = 128, BK = 32;

// ---------------------------------------------------------------------------
__device__ __forceinline__ void async_copy16(const bf16* g, bf16* l) {
    __builtin_amdgcn_global_load_lds(
        (const __attribute__((address_space(1))) void*)g,
        (__attribute__((address_space(3))) void*)l, 16, 0, 0);
}

// ---------------------------------------------------------------------------
// Transpose X [D][NT] fp32 -> Xt [NT][D]: fp32 + split bf16 (hi, lo).
__global__ __launch_bounds__(256)
void transpose_x(const float* __restrict__ in, float* __restrict__ outF,
                 bf16* __restrict__ outHi, bf16* __restrict__ outLo,
                 int R, int C) {
    __shared__ float tile[32][33];
    const int tx = threadIdx.x & 31, ty = threadIdx.x >> 5;
    const int c0 = blockIdx.x * 32, r0 = blockIdx.y * 32;
#pragma unroll
    for (int j = 0; j < 4; j++)
        tile[ty + j * 8][tx] = in[(size_t)(r0 + ty + j * 8) * C + c0 + tx];
    __syncthreads();
#pragma unroll
    for (int j = 0; j < 4; j++) {
        float v = tile[tx][ty + j * 8];
        size_t idx = (size_t)(c0 + ty + j * 8) * R + r0 + tx;
        outF[idx] = v;
        bf16 hi = (bf16)v;
        outHi[idx] = hi;
        outLo[idx] = (bf16)(v - (float)hi);
    }
}

// Transpose 3 weights [D][D] fp32 -> bf16 (z selects which).
__global__ __launch_bounds__(256)
void transpose_w3(const float* __restrict__ w0, const float* __restrict__ w1,
                  const float* __restrict__ w2, bf16* __restrict__ o0,
                  bf16* __restrict__ o1, bf16* __restrict__ o2, int R, int C) {
    const float* in = blockIdx.z == 0 ? w0 : blockIdx.z == 1 ? w1 : w2;
    bf16* out = blockIdx.z == 0 ? o0 : blockIdx.z == 1 ? o1 : o2;
    __shared__ float tile[32][33];
    const int tx = threadIdx.x & 31, ty = threadIdx.x >> 5;
    const int c0 = blockIdx.x * 32, r0 = blockIdx.y * 32;
#pragma unroll
    for (int j = 0; j < 4; j++)
        tile[ty + j * 8][tx] = in[(size_t)(r0 + ty + j * 8) * C + c0 + tx];
    __syncthreads();
#pragma unroll
    for (int j = 0; j < 4; j++)
        out[(size_t)(c0 + ty + j * 8) * R + r0 + tx] = (bf16)tile[tx][ty + j * 8];
}

// Elementwise convert (no transpose): Wq->hi/lo, Wk->hi/lo, Wv->hi.
__global__ __launch_bounds__(256)
void convert_w(const float* __restrict__ w0, const float* __restrict__ w1,
               const float* __restrict__ w2, bf16* __restrict__ h0,
               bf16* __restrict__ l0, bf16* __restrict__ h1,
               bf16* __restrict__ l1, bf16* __restrict__ h2, int n) {
    const float* in = blockIdx.y == 0 ? w0 : blockIdx.y == 1 ? w1 : w2;
    bf16* hi = blockIdx.y == 0 ? h0 : blockIdx.y == 1 ? h1 : h2;
    bf16* lo = blockIdx.y == 0 ? l0 : blockIdx.y == 1 ? l1 : nullptr;
    for (int i = blockIdx.x * 256 + threadIdx.x; i < n; i += 256 * gridDim.x) {
        float v = in[i];
        bf16 h = (bf16)v;
        hi[i] = h;
        if (lo) lo[i] = (bf16)(v - (float)h);
    }
}

// ---------------------------------------------------------------------------
// Causal softmax IN-PLACE: fp32 S row -> bf16 A in same memory (pitch 2N).
__global__ __launch_bounds__(256)
void softmax_causal_inplace(float* __restrict__ S, int N) {
    const int row = blockIdx.x;
    const int len = row + 1;
    float* s = S + (size_t)row * N;
    bf16* a = (bf16*)s;
    __shared__ float red[256];
    const int t = threadIdx.x;

    float v[16];
#pragma unroll
    for (int j = 0; j < 16; j++) v[j] = s[t + j * 256];

    float mx = -1e30f;
#pragma unroll
    for (int j = 0; j < 16; j++) {
        int c = t + j * 256;
        if (c < len) mx = fmaxf(mx, v[j]);
    }
    red[t] = mx; __syncthreads();
    for (int o = 128; o > 0; o >>= 1) { if (t < o) red[t] = fmaxf(red[t], red[t + o]); __syncthreads(); }
    mx = red[0]; __syncthreads();

    float sum = 0.f;
#pragma unroll
    for (int j = 0; j < 16; j++) {
        int c = t + j * 256;
        if (c < len) sum += __expf(v[j] - mx);
    }
    red[t] = sum; __syncthreads();
    for (int o = 128; o > 0; o >>= 1) { if (t < o) red[t] += red[t + o]; __syncthreads(); }
    const float inv = 1.0f / red[0];
#pragma unroll
    for (int j = 0; j < 16; j++) {
        int c = t + j * 256;
        a[c] = (bf16)((c < len) ? __expf(v[j] - mx) * inv : 0.0f);
    }
}

// ---------------------------------------------------------------------------
// Plain bf16 GEMM body: C[m0:,n0:] block of A[M,K]*B[N,K]^T (m97 structure).
// MODE 0: Cb = bf16(acc)
// MODE 2: Cf = acc + resid; Cb = bf16(Cf)
// MODE 3: Cb = bf16(relu(acc))
// MODE 4: Cf[col*M + row] = acc + resid[row*N + col]  (transposed store)
template <int MODE>
__device__ __forceinline__ void plain_body(
    bf16* lA, bf16* lB, const bf16* __restrict__ A, const bf16* __restrict__ B,
    float* __restrict__ Cf, bf16* __restrict__ Cb, const float* __restrict__ resid,
    int m0, int n0, int M, int N, int K, int lda, int Keff) {
    const int t = threadIdx.x;
    const int lane = t & 63, wave = t >> 6;
    const int wm = (wave >> 1) * 64, wn = (wave & 1) * 64;
    const int lm = lane & 15, lq = lane >> 4;
    const int sr = t >> 2, sk = (t & 3) * 8;

    const bf16* ga = A + (size_t)(m0 + sr) * lda + sk;
    const bf16* gb = B + (size_t)(n0 + sr) * K + sk;
    bf16* la = lA + t * 8;
    bf16* lb = lB + t * 8;

    f32x4 acc[4][4] = {};

    for (int k0 = 0; k0 < Keff; k0 += BK) {
        async_copy16(ga + k0, la);
        async_copy16(ga + k0 + (size_t)64 * lda, la + 64 * BK);
        async_copy16(gb + k0, lb);
        async_copy16(gb + k0 + (size_t)64 * K, lb + 64 * BK);
        __syncthreads();

        bf16x8 af[4], bfr[4];
#pragma unroll
        for (int i = 0; i < 4; i++)
            af[i] = *(const bf16x8*)&lA[(wm + i * 16 + lm) * BK + lq * 8];
#pragma unroll
        for (int i = 0; i < 4; i++)
            bfr[i] = *(const bf16x8*)&lB[(wn + i * 16 + lm) * BK + lq * 8];
#pragma unroll
        for (int i = 0; i < 4; i++)
#pragma unroll
            for (int j = 0; j < 4; j++)
                acc[i][j] = __builtin_amdgcn_mfma_f32_16x16x32_bf16(
                    af[i], bfr[j], acc[i][j], 0, 0, 0);
        __syncthreads();
    }

    // C/D layout: col = lane&15, row = (lane>>4)*4 + reg.
#pragma unroll
    for (int i = 0; i < 4; i++) {
        const int row = m0 + wm + i * 16 + lq * 4;
#pragma unroll
        for (int j = 0; j < 4; j++) {
            const int col = n0 + wn + j * 16 + lm;
            f32x4 v = acc[i][j];
            if (MODE == 0) {
#pragma unroll
                for (int r = 0; r < 4; r++)
                    Cb[(size_t)(row + r) * N + col] = (bf16)v[r];
            } else if (MODE == 2) {
#pragma unroll
                for (int r = 0; r < 4; r++) {
                    float o = v[r] + resid[(size_t)(row + r) * N + col];
                    Cf[(size_t)(row + r) * N + col] = o;
                    Cb[(size_t)(row + r) * N + col] = (bf16)o;
                }
            } else if (MODE == 3) {
#pragma unroll
                for (int r = 0; r < 4; r++)
                    Cb[(size_t)(row + r) * N + col] = (bf16)fmaxf(v[r], 0.0f);
            } else {
#pragma unroll
                for (int r = 0; r < 4; r++) {
                    float o = v[r] + resid[(size_t)(row + r) * N + col];
                    Cf[(size_t)col * M + (row + r)] = o;
                }
            }
        }
    }
}

// Split-precision GEMM body: C = (Ahi+Alo)*(Bhi+Blo)^T, 3 MFMA passes.
// MODE 1: Cf = acc
// MODE 5: Chi = bf16(acc); Clo = bf16(acc - Chi)
template <int MODE>
__device__ __forceinline__ void split_body(
    bf16* lAh, bf16* lAl, bf16* lBh, bf16* lBl,
    const bf16* __restrict__ Ahi, const bf16* __restrict__ Alo,
    const bf16* __restrict__ Bhi, const bf16* __restrict__ Blo,
    float* __restrict__ Cf, bf16* __restrict__ Chi, bf16* __restrict__ Clo,
    int m0, int n0, int N, int K) {
    const int t = threadIdx.x;
    const int lane = t & 63, wave = t >> 6;
    const int wm = (wave >> 1) * 64, wn = (wave & 1) * 64;
    const int lm = lane & 15, lq = lane >> 4;
    const int sr = t >> 2, sk = (t & 3) * 8;

    const size_t go = (size_t)(m0 + sr) * K + sk;
    const size_t gBo = (size_t)(n0 + sr) * K + sk;

    f32x4 acc[4][4] = {};

    for (int k0 = 0; k0 < K; k0 += BK) {
        async_copy16(Ahi + go + k0, &lAh[t * 8]);
        async_copy16(Ahi + go + k0 + (size_t)64 * K, &lAh[t * 8 + 64 * BK]);
        async_copy16(Alo + go + k0, &lAl[t * 8]);
        async_copy16(Alo + go + k0 + (size_t)64 * K, &lAl[t * 8 + 64 * BK]);
        async_copy16(Bhi + gBo + k0, &lBh[t * 8]);
        async_copy16(Bhi + gBo + k0 + (size_t)64 * K, &lBh[t * 8 + 64 * BK]);
        async_copy16(Blo + gBo + k0, &lBl[t * 8]);
        async_copy16(Blo + gBo + k0 + (size_t)64 * K, &lBl[t * 8 + 64 * BK]);
        __syncthreads();

        bf16x8 ah[4], al[4], bh[4], bl[4];
#pragma unroll
        for (int i = 0; i < 4; i++) {
            const int ro = (wm + i * 16 + lm) * BK + lq * 8;
            ah[i] = *(const bf16x8*)&lAh[ro];
            al[i] = *(const bf16x8*)&lAl[ro];
        }
#pragma unroll
        for (int j = 0; j < 4; j++) {
            const int ro = (wn + j * 16 + lm) * BK + lq * 8;
            bh[j] = *(const bf16x8*)&lBh[ro];
            bl[j] = *(const bf16x8*)&lBl[ro];
        }
#pragma unroll
        for (int i = 0; i < 4; i++)
#pragma unroll
            for (int j = 0; j < 4; j++) {
                acc[i][j] = __builtin_amdgcn_mfma_f32_16x16x32_bf16(ah[i], bh[j], acc[i][j], 0, 0, 0);
                acc[i][j] = __builtin_amdgcn_mfma_f32_16x16x32_bf16(ah[i], bl[j], acc[i][j], 0, 0, 0);
                acc[i][j] = __builtin_amdgcn_mfma_f32_16x16x32_bf16(al[i], bh[j], acc[i][j], 0, 0, 0);
            }
        __syncthreads();
    }

#pragma unroll
    for (int i = 0; i < 4; i++) {
        const int row = m0 + wm + i * 16 + lq * 4;
#pragma unroll
        for (int j = 0; j < 4; j++) {
            const int col = n0 + wn + j * 16 + lm;
            f32x4 v = acc[i][j];
            if (MODE == 1) {
#pragma unroll
                for (int r = 0; r < 4; r++)
                    Cf[(size_t)(row + r) * N + col] = v[r];
            } else {
#pragma unroll
                for (int r = 0; r < 4; r++) {
                    float f = v[r];
                    bf16 hi = (bf16)f;
                    Chi[(size_t)(row + r) * N + col] = hi;
                    Clo[(size_t)(row + r) * N + col] = (bf16)(f - (float)hi);
                }
            }
        }
    }
}

// ---------------------------------------------------------------------------
// Fused pair: GT = Wk_s * Wq_s^T (split out) ++ HT = Wot * Wv^T (bf16 out).
// Grid: 128 blocks (64 + 64). Both [1024,1024,1024].
__global__ __launch_bounds__(256)
void tiny_pair(const bf16* Wkhi, const bf16* Wklo, const bf16* Wqhi,
               const bf16* Wqlo, bf16* GThi, bf16* GTlo,
               const bf16* Wot, const bf16* Wvb, bf16* HTb) {
    __shared__ alignas(16) bf16 smem[4 * BM * BK];
    const int x = blockIdx.x;
    if (x < 64) {
        const int m0 = (x >> 3) * BM, n0 = (x & 7) * BN;
        split_body<5>(smem, smem + BM * BK, smem + 2 * BM * BK, smem + 3 * BM * BK,
                      Wkhi, Wklo, Wqhi, Wqlo, nullptr, GThi, GTlo, m0, n0, 1024, 1024);
    } else {
        const int r = x - 64;
        const int m0 = (r >> 3) * BM, n0 = (r & 7) * BN;
        plain_body<0>(smem, smem + BM * BK, Wot, Wvb, nullptr, HTb, nullptr,
                      m0, n0, 1024, 1024, 1024, 1024, 1024);
    }
}

// Fused pair: Q' = Xt_s * GT_s^T (split out, [4096,1024,1024])
//          ++ RHt = HT * Xt^T    (bf16 out, [1024,4096,1024]).
// Grid: 512 blocks (256 + 256) -> 2 blocks/CU on the worst-occupancy GEMMs.
__global__ __launch_bounds__(256)
void mid_pair(const bf16* Xhi, const bf16* Xlo, const bf16* GThi,
              const bf16* GTlo, bf16* Qphi, bf16* Qplo,
              const bf16* HTb, bf16* RHt) {
    __shared__ alignas(16) bf16 smem[4 * BM * BK];
    const int x = blockIdx.x;
    if (x < 256) {
        const int m0 = (x >> 3) * BM, n0 = (x & 7) * BN;
        split_body<5>(smem, smem + BM * BK, smem + 2 * BM * BK, smem + 3 * BM * BK,
                      Xhi, Xlo, GThi, GTlo, nullptr, Qphi, Qplo, m0, n0, 1024, 1024);
    } else {
        const int r = x - 256;
        const int m0 = (r & 7) * BM, n0 = (r >> 3) * BN;
        plain_body<0>(smem, smem + BM * BK, HTb, Xhi, nullptr, RHt, nullptr,
                      m0, n0, 1024, 4096, 1024, 1024, 1024);
    }
}

// Scores over lower triangle only: S = Q'_s * Xt_s^T, 528 blocks.
__global__ __launch_bounds__(256)
void scores_tri(const bf16* Qphi, const bf16* Qplo, const bf16* Xhi,
                const bf16* Xlo, float* S) {
    __shared__ alignas(16) bf16 smem[4 * BM * BK];
    const int t = blockIdx.x;
    int bm = (int)((sqrtf(8.0f * (float)t + 1.0f) - 1.0f) * 0.5f);
    while ((bm + 1) * (bm + 2) / 2 <= t) ++bm;
    while (bm * (bm + 1) / 2 > t) --bm;
    const int bn = t - bm * (bm + 1) / 2;
    split_body<1>(smem, smem + BM * BK, smem + 2 * BM * BK, smem + 3 * BM * BK,
                  Qphi, Qplo, Xhi, Xlo, S, nullptr, nullptr,
                  bm * BM, bn * BN, 4096, 1024);
}

// Standalone plain GEMM (16 KB LDS).
template <int MODE, bool CAUSAL_K>
__global__ __launch_bounds__(256)
void gemm_plain(const bf16* __restrict__ A, const bf16* __restrict__ B,
                float* __restrict__ Cf, bf16* __restrict__ Cb,
                const float* __restrict__ resid, int M, int N, int K, int lda) {
    __shared__ alignas(16) bf16 smem[2 * BM * BK];
    const int m0 = blockIdx.y * BM, n0 = blockIdx.x * BN;
    const int Keff = CAUSAL_K ? (K < m0 + BM ? K : m0 + BM) : K;
    plain_body<MODE>(smem, smem + BM * BK, A, B, Cf, Cb, resid,
                     m0, n0, M, N, K, lda, Keff);
}

// ---------------------------------------------------------------------------
extern "C" void kernel_launch(void* const* d_in, const int* in_sizes, int n_in,
                              void* d_out, int out_size, void* d_ws, size_t ws_size,
                              hipStream_t stream) {
    const int D = 1024, NT = 4096;
    const float* X = (const float*)d_in[0];
    const float* W[6] = {(const float*)d_in[1], (const float*)d_in[2],
                         (const float*)d_in[3], (const float*)d_in[4],
                         (const float*)d_in[5], (const float*)d_in[6]};
    char* ws = (char*)d_ws;
    auto MB = [](size_t x) { return x << 20; };

    // Workspace layout (158 MB peak; <=164 MB proven safe in R1):
    float* Xtf  = (float*)(ws + MB(0));    // [NT][D] fp32 residual
    bf16*  Xhi  = (bf16*)(ws + MB(16));
    bf16*  Xlo  = (bf16*)(ws + MB(24));
    bf16*  Wqhi = (bf16*)(ws + MB(32)), *Wqlo = (bf16*)(ws + MB(34));
    bf16*  Wkhi = (bf16*)(ws + MB(36)), *Wklo = (bf16*)(ws + MB(38));
    bf16*  Wvb  = (bf16*)(ws + MB(40));
    bf16*  Wot  = (bf16*)(ws + MB(42));
    bf16*  W4t  = (bf16*)(ws + MB(44));
    bf16*  W5t  = (bf16*)(ws + MB(46));
    bf16*  GThi = (bf16*)(ws + MB(48)), *GTlo = (bf16*)(ws + MB(50));
    bf16*  HTb  = (bf16*)(ws + MB(52));
    bf16*  Qphi = (bf16*)(ws + MB(54));   // [NT][D] (dead after scores)
    bf16*  Qplo = (bf16*)(ws + MB(62));   // [NT][D] (dead after scores)
    float* S    = (float*)(ws + MB(70));  // [NT][NT] fp32 -> A bf16 in-place
    bf16*  RHt  = (bf16*)(ws + MB(134)); // [D][NT]
    float* Y1f  = (float*)(ws + MB(142)); // [NT][D] fp32
    bf16*  Y1b  = (bf16*)(ws + MB(54));  // over Qphi (dead)
    bf16*  hb   = (bf16*)(ws + MB(62));  // over Qplo (dead)
    float* outF = (float*)d_out;          // [D][NT]

    // 1. Prep: X transpose (fp32+split), weight converts/transposes.
    transpose_x<<<dim3(NT / 32, D / 32), 256, 0, stream>>>(X, Xtf, Xhi, Xlo, D, NT);
    convert_w<<<dim3(256, 3), 256, 0, stream>>>(W[0], W[1], W[2], Wqhi, Wqlo,
                                                Wkhi, Wklo, Wvb, D * D);
    transpose_w3<<<dim3(D / 32, D / 32, 3), 256, 0, stream>>>(
        W[3], W[4], W[5], Wot, W4t, W5t, D, D);

    // 2. GT = Wk*Wq^T (split) ++ HT = Wo^T*Wv^T (bf16).
    tiny_pair<<<128, 256, 0, stream>>>(Wkhi, Wklo, Wqhi, Wqlo, GThi, GTlo,
                                       Wot, Wvb, HTb);

    // 3. Q' = Xt*G (split out) ++ RHt = HT*Xt^T (bf16).
    mid_pair<<<512, 256, 0, stream>>>(Xhi, Xlo, GThi, GTlo, Qphi, Qplo, HTb, RHt);

    // 4. Scores over lower triangle (near-fp32).
    scores_tri<<<528, 256, 0, stream>>>(Qphi, Qplo, Xhi, Xlo, S);

    // 5. Softmax in-place (A bf16, pitch 2*NT).
    softmax_causal_inplace<<<NT, 256, 0, stream>>>(S, NT);
    bf16* Ab = (bf16*)S;

    // 6. Y1 = Xt + A@RH (causal-K truncation).
    gemm_plain<2, true><<<dim3(D / BN, NT / BM), 256, 0, stream>>>(
        Ab, RHt, Y1f, Y1b, Xtf, NT, D, NT, 2 * NT);

    // 7. h = relu(Y1 @ mlp_in).
    gemm_plain<3, false><<<dim3(D / BN, NT / BM), 256, 0, stream>>>(
        Y1b, W4t, nullptr, hb, nullptr, NT, D, D, D);

    // 8. out = (Y1 + h @ mlp_out)^T.
    gemm_plain<4, false><<<dim3(D / BN, NT / BM), 256, 0, stream>>>(
        hb, W5t, outF, nullptr, Y1f, NT, D, D, D);
}

// Round 5
// 328.678 us; speedup vs baseline: 1.6079x; 1.3454x over previous
//
#include <hip/hip_runtime.h>
#include <stdint.h>
#include <stddef.h>

using f16 = _Float16;
typedef __attribute__((ext_vector_type(8))) _Float16 f16x8;
typedef __attribute__((ext_vector_type(4))) float f32x4;

constexpr int BM = 128, BN = 128, BK = 32;

// ---------------------------------------------------------------------------
__device__ __forceinline__ void async_copy16(const f16* g, f16* l) {
    __builtin_amdgcn_global_load_lds(
        (const __attribute__((address_space(1))) void*)g,
        (__attribute__((address_space(3))) void*)l, 16, 0, 0);
}

// ---------------------------------------------------------------------------
// Transpose X [D][NT] fp32 -> Xt [NT][D] fp32 + fp16.
__global__ __launch_bounds__(256)
void transpose_x(const float* __restrict__ in, float* __restrict__ outF,
                 f16* __restrict__ outH, int R, int C) {
    __shared__ float tile[32][33];
    const int tx = threadIdx.x & 31, ty = threadIdx.x >> 5;
    const int c0 = blockIdx.x * 32, r0 = blockIdx.y * 32;
#pragma unroll
    for (int j = 0; j < 4; j++)
        tile[ty + j * 8][tx] = in[(size_t)(r0 + ty + j * 8) * C + c0 + tx];
    __syncthreads();
#pragma unroll
    for (int j = 0; j < 4; j++) {
        float v = tile[tx][ty + j * 8];
        size_t idx = (size_t)(c0 + ty + j * 8) * R + r0 + tx;
        outF[idx] = v;
        outH[idx] = (f16)v;
    }
}

// Weight prep: z<3 -> fp16 convert (Wq, Wk, Wv); z>=3 -> fp16 transpose
// (Wo, mlp_in, mlp_out).
__global__ __launch_bounds__(256)
void prep_w(const float* __restrict__ w0, const float* __restrict__ w1,
            const float* __restrict__ w2, const float* __restrict__ w3,
            const float* __restrict__ w4, const float* __restrict__ w5,
            f16* o0, f16* o1, f16* o2, f16* o3, f16* o4, f16* o5, int D) {
    const int z = blockIdx.z;
    const float* in = z == 0 ? w0 : z == 1 ? w1 : z == 2 ? w2 : z == 3 ? w3 : z == 4 ? w4 : w5;
    f16* out = z == 0 ? o0 : z == 1 ? o1 : z == 2 ? o2 : z == 3 ? o3 : z == 4 ? o4 : o5;
    const int tx = threadIdx.x & 31, ty = threadIdx.x >> 5;
    const int c0 = blockIdx.x * 32, r0 = blockIdx.y * 32;
    if (z < 3) {
#pragma unroll
        for (int j = 0; j < 4; j++) {
            size_t idx = (size_t)(r0 + ty + j * 8) * D + c0 + tx;
            out[idx] = (f16)in[idx];
        }
    } else {
        __shared__ float tile[32][33];
#pragma unroll
        for (int j = 0; j < 4; j++)
            tile[ty + j * 8][tx] = in[(size_t)(r0 + ty + j * 8) * D + c0 + tx];
        __syncthreads();
#pragma unroll
        for (int j = 0; j < 4; j++)
            out[(size_t)(c0 + ty + j * 8) * D + r0 + tx] = (f16)tile[tx][ty + j * 8];
    }
}

// ---------------------------------------------------------------------------
// Causal softmax IN-PLACE: fp32 S row -> fp16 A in same memory (pitch 2N).
__global__ __launch_bounds__(256)
void softmax_causal_inplace(float* __restrict__ S, int N) {
    const int row = blockIdx.x;
    const int len = row + 1;
    float* s = S + (size_t)row * N;
    f16* a = (f16*)s;
    __shared__ float red[256];
    const int t = threadIdx.x;

    float v[16];
    float mx = -1e30f;
#pragma unroll
    for (int j = 0; j < 16; j++) {
        int c = t + j * 256;
        if (c < len) { v[j] = s[c]; mx = fmaxf(mx, v[j]); }
    }
    red[t] = mx; __syncthreads();
    for (int o = 128; o > 0; o >>= 1) { if (t < o) red[t] = fmaxf(red[t], red[t + o]); __syncthreads(); }
    mx = red[0]; __syncthreads();

    float sum = 0.f;
#pragma unroll
    for (int j = 0; j < 16; j++) {
        int c = t + j * 256;
        if (c < len) sum += __expf(v[j] - mx);
    }
    red[t] = sum; __syncthreads();
    for (int o = 128; o > 0; o >>= 1) { if (t < o) red[t] += red[t + o]; __syncthreads(); }
    const float inv = 1.0f / red[0];
#pragma unroll
    for (int j = 0; j < 16; j++) {
        int c = t + j * 256;
        a[c] = (f16)((c < len) ? __expf(v[j] - mx) * inv : 0.0f);
    }
}

// ---------------------------------------------------------------------------
// 128x128x32 fp16 GEMM body (m97 structure): C = A[M,K]*B[N,K]^T block.
// MODE 0: Ch = f16(acc);  MODE 1: Cf = acc.
template <int MODE>
__device__ __forceinline__ void plain_body(
    f16* lA, f16* lB, const f16* __restrict__ A, const f16* __restrict__ B,
    float* __restrict__ Cf, f16* __restrict__ Ch,
    int m0, int n0, int N, int K, int lda) {
    const int t = threadIdx.x;
    const int lane = t & 63, wave = t >> 6;
    const int wm = (wave >> 1) * 64, wn = (wave & 1) * 64;
    const int lm = lane & 15, lq = lane >> 4;
    const int sr = t >> 2, sk = (t & 3) * 8;

    const f16* ga = A + (size_t)(m0 + sr) * lda + sk;
    const f16* gb = B + (size_t)(n0 + sr) * K + sk;
    f16* la = lA + t * 8;
    f16* lb = lB + t * 8;

    f32x4 acc[4][4] = {};

    for (int k0 = 0; k0 < K; k0 += BK) {
        async_copy16(ga + k0, la);
        async_copy16(ga + k0 + (size_t)64 * lda, la + 64 * BK);
        async_copy16(gb + k0, lb);
        async_copy16(gb + k0 + (size_t)64 * K, lb + 64 * BK);
        __syncthreads();

        f16x8 af[4], bfr[4];
#pragma unroll
        for (int i = 0; i < 4; i++)
            af[i] = *(const f16x8*)&lA[(wm + i * 16 + lm) * BK + lq * 8];
#pragma unroll
        for (int i = 0; i < 4; i++)
            bfr[i] = *(const f16x8*)&lB[(wn + i * 16 + lm) * BK + lq * 8];
#pragma unroll
        for (int i = 0; i < 4; i++)
#pragma unroll
            for (int j = 0; j < 4; j++)
                acc[i][j] = __builtin_amdgcn_mfma_f32_16x16x32_f16(
                    af[i], bfr[j], acc[i][j], 0, 0, 0);
        __syncthreads();
    }

    // C/D layout: col = lane&15, row = (lane>>4)*4 + reg.
#pragma unroll
    for (int i = 0; i < 4; i++) {
        const int row = m0 + wm + i * 16 + lq * 4;
#pragma unroll
        for (int j = 0; j < 4; j++) {
            const int col = n0 + wn + j * 16 + lm;
            f32x4 v = acc[i][j];
#pragma unroll
            for (int r = 0; r < 4; r++) {
                if (MODE == 0) Ch[(size_t)(row + r) * N + col] = (f16)v[r];
                else           Cf[(size_t)(row + r) * N + col] = v[r];
            }
        }
    }
}

// ---------------------------------------------------------------------------
// 128x64x32 fp16 GEMM body: 4 waves stacked on M (32 rows each), 64 cols.
// A tile: 128x32 = 4096 elem -> 256 threads x 2 copies.
// B tile:  64x32 = 2048 elem -> 256 threads x 1 copy (ALL threads; sr=t>>2
// spans rows 0..63 — the R4 bug was guarding this to t<128, staging only
// half the tile).
// MODE 2: Cf = acc + resid; Ch = f16(Cf)
// MODE 3: Ch = f16(relu(acc))
// MODE 4: Cf[col*M + row] = acc + resid[row*N + col]   (transposed store)
template <int MODE>
__device__ __forceinline__ void narrow_body(
    f16* lA, f16* lB, const f16* __restrict__ A, const f16* __restrict__ B,
    float* __restrict__ Cf, f16* __restrict__ Ch, const float* __restrict__ resid,
    int m0, int n0, int M, int N, int K, int lda, int Keff) {
    const int t = threadIdx.x;
    const int lane = t & 63, wave = t >> 6;
    const int lm = lane & 15, lq = lane >> 4;
    const int sr = t >> 2, sk = (t & 3) * 8;

    const f16* ga = A + (size_t)(m0 + sr) * lda + sk;
    const f16* gb = B + (size_t)(n0 + sr) * K + sk;
    f16* la = lA + t * 8;
    f16* lb = lB + t * 8;

    f32x4 acc[2][4] = {};

    for (int k0 = 0; k0 < Keff; k0 += BK) {
        async_copy16(ga + k0, la);
        async_copy16(ga + k0 + (size_t)64 * lda, la + 64 * BK);
        async_copy16(gb + k0, lb);   // full 64-row B tile, all 256 threads
        __syncthreads();

        f16x8 af[2], bfr[4];
#pragma unroll
        for (int i = 0; i < 2; i++)
            af[i] = *(const f16x8*)&lA[(wave * 32 + i * 16 + lm) * BK + lq * 8];
#pragma unroll
        for (int j = 0; j < 4; j++)
            bfr[j] = *(const f16x8*)&lB[(j * 16 + lm) * BK + lq * 8];
#pragma unroll
        for (int i = 0; i < 2; i++)
#pragma unroll
            for (int j = 0; j < 4; j++)
                acc[i][j] = __builtin_amdgcn_mfma_f32_16x16x32_f16(
                    af[i], bfr[j], acc[i][j], 0, 0, 0);
        __syncthreads();
    }

#pragma unroll
    for (int i = 0; i < 2; i++) {
        const int row = m0 + wave * 32 + i * 16 + lq * 4;
#pragma unroll
        for (int j = 0; j < 4; j++) {
            const int col = n0 + j * 16 + lm;
            f32x4 v = acc[i][j];
#pragma unroll
            for (int r = 0; r < 4; r++) {
                if (MODE == 2) {
                    float o = v[r] + resid[(size_t)(row + r) * N + col];
                    Cf[(size_t)(row + r) * N + col] = o;
                    Ch[(size_t)(row + r) * N + col] = (f16)o;
                } else if (MODE == 3) {
                    Ch[(size_t)(row + r) * N + col] = (f16)fmaxf(v[r], 0.0f);
                } else {
                    float o = v[r] + resid[(size_t)(row + r) * N + col];
                    Cf[(size_t)col * M + (row + r)] = o;
                }
            }
        }
    }
}

// ---------------------------------------------------------------------------
// Fused: GT = Wk*Wq^T ++ HT = Wo^T*Wv^T, both [1024^3], 128 blocks.
__global__ __launch_bounds__(256)
void tiny_pair(const f16* Wkh, const f16* Wqh, f16* GT,
               const f16* Wot, const f16* Wvh, f16* HT) {
    __shared__ alignas(16) f16 smem[2 * BM * BK];
    const int x = blockIdx.x;
    if (x < 64) {
        plain_body<0>(smem, smem + BM * BK, Wkh, Wqh, nullptr, GT,
                      (x >> 3) * BM, (x & 7) * BN, 1024, 1024, 1024);
    } else {
        const int r = x - 64;
        plain_body<0>(smem, smem + BM * BK, Wot, Wvh, nullptr, HT,
                      (r >> 3) * BM, (r & 7) * BN, 1024, 1024, 1024);
    }
}

// Fused: Q' = Xt*GT^T [4096,1024,1024] ++ RHt = HT*Xt^T [1024,4096,1024].
__global__ __launch_bounds__(256)
void mid_pair(const f16* Xth, const f16* GT, f16* Qp,
              const f16* HT, f16* RHt) {
    __shared__ alignas(16) f16 smem[2 * BM * BK];
    const int x = blockIdx.x;
    if (x < 256) {
        plain_body<0>(smem, smem + BM * BK, Xth, GT, nullptr, Qp,
                      (x >> 3) * BM, (x & 7) * BN, 1024, 1024, 1024);
    } else {
        const int r = x - 256;
        plain_body<0>(smem, smem + BM * BK, HT, Xth, nullptr, RHt,
                      (r & 7) * BM, (r >> 3) * BN, 4096, 1024, 1024);
    }
}

// Scores over lower triangle: S = Q'*Xt^T, fp32 out, 528 blocks.
__global__ __launch_bounds__(256)
void scores_tri(const f16* Qp, const f16* Xth, float* S) {
    __shared__ alignas(16) f16 smem[2 * BM * BK];
    const int t = blockIdx.x;
    int bm = (int)((sqrtf(8.0f * (float)t + 1.0f) - 1.0f) * 0.5f);
    while ((bm + 1) * (bm + 2) / 2 <= t) ++bm;
    while (bm * (bm + 1) / 2 > t) --bm;
    const int bn = t - bm * (bm + 1) / 2;
    plain_body<1>(smem, smem + BM * BK, Qp, Xth, S, nullptr,
                  bm * BM, bn * BN, 4096, 1024, 1024);
}

// Standalone narrow GEMM (grid: x = N/64, y = M/128).
template <int MODE, bool CAUSAL_K>
__global__ __launch_bounds__(256)
void gemm_narrow(const f16* __restrict__ A, const f16* __restrict__ B,
                 float* __restrict__ Cf, f16* __restrict__ Ch,
                 const float* __restrict__ resid, int M, int N, int K, int lda) {
    __shared__ alignas(16) f16 smem[BM * BK + 64 * BK];
    const int m0 = blockIdx.y * BM, n0 = blockIdx.x * 64;
    const int Keff = CAUSAL_K ? (K < m0 + BM ? K : m0 + BM) : K;
    narrow_body<MODE>(smem, smem + BM * BK, A, B, Cf, Ch, resid,
                      m0, n0, M, N, K, lda, Keff);
}

// ---------------------------------------------------------------------------
extern "C" void kernel_launch(void* const* d_in, const int* in_sizes, int n_in,
                              void* d_out, int out_size, void* d_ws, size_t ws_size,
                              hipStream_t stream) {
    const int D = 1024, NT = 4096;
    const float* X = (const float*)d_in[0];
    const float* W[6] = {(const float*)d_in[1], (const float*)d_in[2],
                         (const float*)d_in[3], (const float*)d_in[4],
                         (const float*)d_in[5], (const float*)d_in[6]};
    char* ws = (char*)d_ws;
    auto MB = [](size_t x) { return x << 20; };

    // Workspace (144 MB peak):
    float* Xtf  = (float*)(ws + MB(0));    // [NT][D] fp32 residual
    f16*   Xth  = (f16*)(ws + MB(16));     // [NT][D]
    f16*   Wqh  = (f16*)(ws + MB(24));
    f16*   Wkh  = (f16*)(ws + MB(26));
    f16*   Wvh  = (f16*)(ws + MB(28));
    f16*   Wot  = (f16*)(ws + MB(30));
    f16*   W4t  = (f16*)(ws + MB(32));
    f16*   W5t  = (f16*)(ws + MB(34));
    f16*   GT   = (f16*)(ws + MB(36));     // [D][D]
    f16*   HT   = (f16*)(ws + MB(38));     // [D][D]
    f16*   Qp   = (f16*)(ws + MB(40));     // [NT][D] (dead after scores)
    float* S    = (float*)(ws + MB(48));   // [NT][NT] fp32 -> A f16 in-place
    f16*   RHt  = (f16*)(ws + MB(112));    // [D][NT]
    float* Y1f  = (float*)(ws + MB(120));  // [NT][D] fp32
    f16*   Y1h  = (f16*)(ws + MB(136));    // [NT][D]
    f16*   hb   = (f16*)(ws + MB(40));     // over Qp (dead)
    float* outF = (float*)d_out;           // [D][NT]

    // 1. Prep.
    transpose_x<<<dim3(NT / 32, D / 32), 256, 0, stream>>>(X, Xtf, Xth, D, NT);
    prep_w<<<dim3(D / 32, D / 32, 6), 256, 0, stream>>>(
        W[0], W[1], W[2], W[3], W[4], W[5], Wqh, Wkh, Wvh, Wot, W4t, W5t, D);

    // 2. GT = Wk*Wq^T ++ HT = Wo^T*Wv^T.
    tiny_pair<<<128, 256, 0, stream>>>(Wkh, Wqh, GT, Wot, Wvh, HT);

    // 3. Q' = Xt*G ++ RHt = HT*Xt^T.
    mid_pair<<<512, 256, 0, stream>>>(Xth, GT, Qp, HT, RHt);

    // 4. Scores (lower triangle, fp32).
    scores_tri<<<528, 256, 0, stream>>>(Qp, Xth, S);

    // 5. Softmax in-place (A f16, pitch 2*NT).
    softmax_causal_inplace<<<NT, 256, 0, stream>>>(S, NT);
    f16* Ab = (f16*)S;

    // 6. Y1 = Xt + A@RH (causal-K truncation).
    gemm_narrow<2, true><<<dim3(D / 64, NT / BM), 256, 0, stream>>>(
        Ab, RHt, Y1f, Y1h, Xtf, NT, D, NT, 2 * NT);

    // 7. h = relu(Y1 @ mlp_in).
    gemm_narrow<3, false><<<dim3(D / 64, NT / BM), 256, 0, stream>>>(
        Y1h, W4t, nullptr, hb, nullptr, NT, D, D, D);

    // 8. out = (Y1 + h @ mlp_out)^T.
    gemm_narrow<4, false><<<dim3(D / 64, NT / BM), 256, 0, stream>>>(
        hb, W5t, outF, nullptr, Y1f, NT, D, D, D);
}

// Round 6
// 292.990 us; speedup vs baseline: 1.8037x; 1.1218x over previous
//
#include <hip/hip_runtime.h>
#include <stdint.h>
#include <stddef.h>

using f16 = _Float16;
typedef __attribute__((ext_vector_type(8))) _Float16 f16x8;
typedef __attribute__((ext_vector_type(4))) float f32x4;

constexpr int BM = 128, BN = 128;

// ---------------------------------------------------------------------------
__device__ __forceinline__ void async_copy16(const f16* g, f16* l) {
    __builtin_amdgcn_global_load_lds(
        (const __attribute__((address_space(1))) void*)g,
        (__attribute__((address_space(3))) void*)l, 16, 0, 0);
}

// ---------------------------------------------------------------------------
// Transpose X [D][NT] fp32 -> Xt [NT][D] fp32 + fp16.
__global__ __launch_bounds__(256)
void transpose_x(const float* __restrict__ in, float* __restrict__ outF,
                 f16* __restrict__ outH, int R, int C) {
    __shared__ float tile[32][33];
    const int tx = threadIdx.x & 31, ty = threadIdx.x >> 5;
    const int c0 = blockIdx.x * 32, r0 = blockIdx.y * 32;
#pragma unroll
    for (int j = 0; j < 4; j++)
        tile[ty + j * 8][tx] = in[(size_t)(r0 + ty + j * 8) * C + c0 + tx];
    __syncthreads();
#pragma unroll
    for (int j = 0; j < 4; j++) {
        float v = tile[tx][ty + j * 8];
        size_t idx = (size_t)(c0 + ty + j * 8) * R + r0 + tx;
        outF[idx] = v;
        outH[idx] = (f16)v;
    }
}

// Weight prep: z<3 -> fp16 convert (Wq, Wk, Wv); z>=3 -> fp16 transpose.
__global__ __launch_bounds__(256)
void prep_w(const float* __restrict__ w0, const float* __restrict__ w1,
            const float* __restrict__ w2, const float* __restrict__ w3,
            const float* __restrict__ w4, const float* __restrict__ w5,
            f16* o0, f16* o1, f16* o2, f16* o3, f16* o4, f16* o5, int D) {
    const int z = blockIdx.z;
    const float* in = z == 0 ? w0 : z == 1 ? w1 : z == 2 ? w2 : z == 3 ? w3 : z == 4 ? w4 : w5;
    f16* out = z == 0 ? o0 : z == 1 ? o1 : z == 2 ? o2 : z == 3 ? o3 : z == 4 ? o4 : o5;
    const int tx = threadIdx.x & 31, ty = threadIdx.x >> 5;
    const int c0 = blockIdx.x * 32, r0 = blockIdx.y * 32;
    if (z < 3) {
#pragma unroll
        for (int j = 0; j < 4; j++) {
            size_t idx = (size_t)(r0 + ty + j * 8) * D + c0 + tx;
            out[idx] = (f16)in[idx];
        }
    } else {
        __shared__ float tile[32][33];
#pragma unroll
        for (int j = 0; j < 4; j++)
            tile[ty + j * 8][tx] = in[(size_t)(r0 + ty + j * 8) * D + c0 + tx];
        __syncthreads();
#pragma unroll
        for (int j = 0; j < 4; j++)
            out[(size_t)(c0 + ty + j * 8) * D + r0 + tx] = (f16)tile[tx][ty + j * 8];
    }
}

// ---------------------------------------------------------------------------
// Causal softmax IN-PLACE: fp32 S row -> fp16 A in same memory (pitch 2N).
__global__ __launch_bounds__(256)
void softmax_causal_inplace(float* __restrict__ S, int N) {
    const int row = blockIdx.x;
    const int len = row + 1;
    float* s = S + (size_t)row * N;
    f16* a = (f16*)s;
    __shared__ float red[256];
    const int t = threadIdx.x;

    float v[16];
    float mx = -1e30f;
#pragma unroll
    for (int j = 0; j < 16; j++) {
        int c = t + j * 256;
        if (c < len) { v[j] = s[c]; mx = fmaxf(mx, v[j]); }
    }
    red[t] = mx; __syncthreads();
    for (int o = 128; o > 0; o >>= 1) { if (t < o) red[t] = fmaxf(red[t], red[t + o]); __syncthreads(); }
    mx = red[0]; __syncthreads();

    float sum = 0.f;
#pragma unroll
    for (int j = 0; j < 16; j++) {
        int c = t + j * 256;
        if (c < len) sum += __expf(v[j] - mx);
    }
    red[t] = sum; __syncthreads();
    for (int o = 128; o > 0; o >>= 1) { if (t < o) red[t] += red[t + o]; __syncthreads(); }
    const float inv = 1.0f / red[0];
#pragma unroll
    for (int j = 0; j < 16; j++) {
        int c = t + j * 256;
        a[c] = (f16)((c < len) ? __expf(v[j] - mx) * inv : 0.0f);
    }
}

// ---------------------------------------------------------------------------
// 128x128x64 fp16 GEMM body. LDS layout per operand: two stacked BK=32
// half-tiles [2][128][32] so global_load_lds dests stay contiguous (t*8)
// while fragment reads keep the proven BK=32 addressing (no new bank
// conflicts). One barrier pair per 64 K (half the drains of BK=32).
// MODE 0: Ch = f16(acc);  MODE 1: Cf = acc.
template <int MODE>
__device__ __forceinline__ void plain_body(
    f16* lA, f16* lB, const f16* __restrict__ A, const f16* __restrict__ B,
    float* __restrict__ Cf, f16* __restrict__ Ch,
    int m0, int n0, int N, int K, int lda) {
    const int t = threadIdx.x;
    const int lane = t & 63, wave = t >> 6;
    const int wm = (wave >> 1) * 64, wn = (wave & 1) * 64;
    const int lm = lane & 15, lq = lane >> 4;
    const int sr = t >> 2;        // 0..63
    const int sc = (t & 3) * 8;   // 0,8,16,24

    f32x4 acc[4][4] = {};

    for (int k0 = 0; k0 < K; k0 += 64) {
#pragma unroll
        for (int r = 0; r < 4; r++) {  // round r: rows +r&1*64, K-half r>>1
            const int row = sr + (r & 1) * 64;
            const int col = k0 + (r >> 1) * 32 + sc;
            async_copy16(A + (size_t)(m0 + row) * lda + col, lA + r * 2048 + t * 8);
        }
#pragma unroll
        for (int r = 0; r < 4; r++) {
            const int row = sr + (r & 1) * 64;
            const int col = k0 + (r >> 1) * 32 + sc;
            async_copy16(B + (size_t)(n0 + row) * K + col, lB + r * 2048 + t * 8);
        }
        __syncthreads();

#pragma unroll
        for (int kk = 0; kk < 2; kk++) {
            f16x8 af[4], bfr[4];
#pragma unroll
            for (int i = 0; i < 4; i++)
                af[i] = *(const f16x8*)&lA[kk * 4096 + (wm + i * 16 + lm) * 32 + lq * 8];
#pragma unroll
            for (int j = 0; j < 4; j++)
                bfr[j] = *(const f16x8*)&lB[kk * 4096 + (wn + j * 16 + lm) * 32 + lq * 8];
#pragma unroll
            for (int i = 0; i < 4; i++)
#pragma unroll
                for (int j = 0; j < 4; j++)
                    acc[i][j] = __builtin_amdgcn_mfma_f32_16x16x32_f16(
                        af[i], bfr[j], acc[i][j], 0, 0, 0);
        }
        __syncthreads();
    }

    // C/D layout: col = lane&15, row = (lane>>4)*4 + reg.
#pragma unroll
    for (int i = 0; i < 4; i++) {
        const int row = m0 + wm + i * 16 + lq * 4;
#pragma unroll
        for (int j = 0; j < 4; j++) {
            const int col = n0 + wn + j * 16 + lm;
            f32x4 v = acc[i][j];
#pragma unroll
            for (int r = 0; r < 4; r++) {
                if (MODE == 0) Ch[(size_t)(row + r) * N + col] = (f16)v[r];
                else           Cf[(size_t)(row + r) * N + col] = v[r];
            }
        }
    }
}

// ---------------------------------------------------------------------------
// 128x64x64 fp16 GEMM body: 4 waves stacked on M (32 rows each), 64 cols.
// A: [2][128][32] staged in 4 rounds; B: [2][64][32] in 2 rounds (all 256
// threads — R4's half-tile bug fixed in R5 and kept fixed here).
// MODE 2: Cf = acc + resid; Ch = f16(Cf)
// MODE 3: Ch = f16(relu(acc))
// MODE 4: Cf[col*M + row] = acc + resid[row*N + col]   (transposed store)
template <int MODE>
__device__ __forceinline__ void narrow_body(
    f16* lA, f16* lB, const f16* __restrict__ A, const f16* __restrict__ B,
    float* __restrict__ Cf, f16* __restrict__ Ch, const float* __restrict__ resid,
    int m0, int n0, int M, int N, int K, int lda, int Keff) {
    const int t = threadIdx.x;
    const int lane = t & 63, wave = t >> 6;
    const int lm = lane & 15, lq = lane >> 4;
    const int sr = t >> 2;
    const int sc = (t & 3) * 8;

    f32x4 acc[2][4] = {};

    for (int k0 = 0; k0 < Keff; k0 += 64) {
#pragma unroll
        for (int r = 0; r < 4; r++) {
            const int row = sr + (r & 1) * 64;
            const int col = k0 + (r >> 1) * 32 + sc;
            async_copy16(A + (size_t)(m0 + row) * lda + col, lA + r * 2048 + t * 8);
        }
#pragma unroll
        for (int r = 0; r < 2; r++) {  // B: 64 rows, K-half r
            const int col = k0 + r * 32 + sc;
            async_copy16(B + (size_t)(n0 + sr) * K + col, lB + r * 2048 + t * 8);
        }
        __syncthreads();

#pragma unroll
        for (int kk = 0; kk < 2; kk++) {
            f16x8 af[2], bfr[4];
#pragma unroll
            for (int i = 0; i < 2; i++)
                af[i] = *(const f16x8*)&lA[kk * 4096 + (wave * 32 + i * 16 + lm) * 32 + lq * 8];
#pragma unroll
            for (int j = 0; j < 4; j++)
                bfr[j] = *(const f16x8*)&lB[kk * 2048 + (j * 16 + lm) * 32 + lq * 8];
#pragma unroll
            for (int i = 0; i < 2; i++)
#pragma unroll
                for (int j = 0; j < 4; j++)
                    acc[i][j] = __builtin_amdgcn_mfma_f32_16x16x32_f16(
                        af[i], bfr[j], acc[i][j], 0, 0, 0);
        }
        __syncthreads();
    }

#pragma unroll
    for (int i = 0; i < 2; i++) {
        const int row = m0 + wave * 32 + i * 16 + lq * 4;
#pragma unroll
        for (int j = 0; j < 4; j++) {
            const int col = n0 + j * 16 + lm;
            f32x4 v = acc[i][j];
#pragma unroll
            for (int r = 0; r < 4; r++) {
                if (MODE == 2) {
                    float o = v[r] + resid[(size_t)(row + r) * N + col];
                    Cf[(size_t)(row + r) * N + col] = o;
                    Ch[(size_t)(row + r) * N + col] = (f16)o;
                } else if (MODE == 3) {
                    Ch[(size_t)(row + r) * N + col] = (f16)fmaxf(v[r], 0.0f);
                } else {
                    float o = v[r] + resid[(size_t)(row + r) * N + col];
                    Cf[(size_t)col * M + (row + r)] = o;
                }
            }
        }
    }
}

// ---------------------------------------------------------------------------
// Fused: GT = Wk*Wq^T ++ HT = Wo^T*Wv^T, both [1024^3], 128 blocks.
__global__ __launch_bounds__(256)
void tiny_pair(const f16* Wkh, const f16* Wqh, f16* GT,
               const f16* Wot, const f16* Wvh, f16* HT) {
    __shared__ alignas(16) f16 smem[2 * 8192];
    const int x = blockIdx.x;
    if (x < 64) {
        plain_body<0>(smem, smem + 8192, Wkh, Wqh, nullptr, GT,
                      (x >> 3) * BM, (x & 7) * BN, 1024, 1024, 1024);
    } else {
        const int r = x - 64;
        plain_body<0>(smem, smem + 8192, Wot, Wvh, nullptr, HT,
                      (r >> 3) * BM, (r & 7) * BN, 1024, 1024, 1024);
    }
}

// Fused: Q' = Xt*GT^T [4096,1024,1024] ++ RHt = HT*Xt^T [1024,4096,1024].
__global__ __launch_bounds__(256)
void mid_pair(const f16* Xth, const f16* GT, f16* Qp,
              const f16* HT, f16* RHt) {
    __shared__ alignas(16) f16 smem[2 * 8192];
    const int x = blockIdx.x;
    if (x < 256) {
        plain_body<0>(smem, smem + 8192, Xth, GT, nullptr, Qp,
                      (x >> 3) * BM, (x & 7) * BN, 1024, 1024, 1024);
    } else {
        const int r = x - 256;
        plain_body<0>(smem, smem + 8192, HT, Xth, nullptr, RHt,
                      (r & 7) * BM, (r >> 3) * BN, 4096, 1024, 1024);
    }
}

// Scores over lower triangle: S = Q'*Xt^T, fp32 out, 528 blocks.
__global__ __launch_bounds__(256)
void scores_tri(const f16* Qp, const f16* Xth, float* S) {
    __shared__ alignas(16) f16 smem[2 * 8192];
    const int t = blockIdx.x;
    int bm = (int)((sqrtf(8.0f * (float)t + 1.0f) - 1.0f) * 0.5f);
    while ((bm + 1) * (bm + 2) / 2 <= t) ++bm;
    while (bm * (bm + 1) / 2 > t) --bm;
    const int bn = t - bm * (bm + 1) / 2;
    plain_body<1>(smem, smem + 8192, Qp, Xth, S, nullptr,
                  bm * BM, bn * BN, 4096, 1024, 1024);
}

// Standalone narrow GEMM. LPT: 1D grid of 512, longest-K blocks first
// (m = 31 - b>>4) -> near-optimal makespan for the causal A@RH.
template <int MODE, bool CAUSAL_K, bool LPT>
__global__ __launch_bounds__(256)
void gemm_narrow(const f16* __restrict__ A, const f16* __restrict__ B,
                 float* __restrict__ Cf, f16* __restrict__ Ch,
                 const float* __restrict__ resid, int M, int N, int K, int lda) {
    __shared__ alignas(16) f16 smem[8192 + 4096];
    int bx, by;
    if (LPT) { by = 31 - ((int)blockIdx.x >> 4); bx = (int)blockIdx.x & 15; }
    else     { bx = blockIdx.x; by = blockIdx.y; }
    const int m0 = by * BM, n0 = bx * 64;
    const int Keff = CAUSAL_K ? (K < m0 + BM ? K : m0 + BM) : K;
    narrow_body<MODE>(smem, smem + 8192, A, B, Cf, Ch, resid,
                      m0, n0, M, N, K, lda, Keff);
}

// ---------------------------------------------------------------------------
extern "C" void kernel_launch(void* const* d_in, const int* in_sizes, int n_in,
                              void* d_out, int out_size, void* d_ws, size_t ws_size,
                              hipStream_t stream) {
    const int D = 1024, NT = 4096;
    const float* X = (const float*)d_in[0];
    const float* W[6] = {(const float*)d_in[1], (const float*)d_in[2],
                         (const float*)d_in[3], (const float*)d_in[4],
                         (const float*)d_in[5], (const float*)d_in[6]};
    char* ws = (char*)d_ws;
    auto MB = [](size_t x) { return x << 20; };

    // Workspace (144 MB peak):
    float* Xtf  = (float*)(ws + MB(0));    // [NT][D] fp32 residual
    f16*   Xth  = (f16*)(ws + MB(16));     // [NT][D]
    f16*   Wqh  = (f16*)(ws + MB(24));
    f16*   Wkh  = (f16*)(ws + MB(26));
    f16*   Wvh  = (f16*)(ws + MB(28));
    f16*   Wot  = (f16*)(ws + MB(30));
    f16*   W4t  = (f16*)(ws + MB(32));
    f16*   W5t  = (f16*)(ws + MB(34));
    f16*   GT   = (f16*)(ws + MB(36));     // [D][D]
    f16*   HT   = (f16*)(ws + MB(38));     // [D][D]
    f16*   Qp   = (f16*)(ws + MB(40));     // [NT][D] (dead after scores)
    float* S    = (float*)(ws + MB(48));   // [NT][NT] fp32 -> A f16 in-place
    f16*   RHt  = (f16*)(ws + MB(112));    // [D][NT]
    float* Y1f  = (float*)(ws + MB(120));  // [NT][D] fp32
    f16*   Y1h  = (f16*)(ws + MB(136));    // [NT][D]
    f16*   hb   = (f16*)(ws + MB(40));     // over Qp (dead)
    float* outF = (float*)d_out;           // [D][NT]

    // 1. Prep.
    transpose_x<<<dim3(NT / 32, D / 32), 256, 0, stream>>>(X, Xtf, Xth, D, NT);
    prep_w<<<dim3(D / 32, D / 32, 6), 256, 0, stream>>>(
        W[0], W[1], W[2], W[3], W[4], W[5], Wqh, Wkh, Wvh, Wot, W4t, W5t, D);

    // 2. GT = Wk*Wq^T ++ HT = Wo^T*Wv^T.
    tiny_pair<<<128, 256, 0, stream>>>(Wkh, Wqh, GT, Wot, Wvh, HT);

    // 3. Q' = Xt*G ++ RHt = HT*Xt^T.
    mid_pair<<<512, 256, 0, stream>>>(Xth, GT, Qp, HT, RHt);

    // 4. Scores (lower triangle, fp32).
    scores_tri<<<528, 256, 0, stream>>>(Qp, Xth, S);

    // 5. Softmax in-place (A f16, pitch 2*NT).
    softmax_causal_inplace<<<NT, 256, 0, stream>>>(S, NT);
    f16* Ab = (f16*)S;

    // 6. Y1 = Xt + A@RH (causal-K truncation, LPT-balanced).
    gemm_narrow<2, true, true><<<512, 256, 0, stream>>>(
        Ab, RHt, Y1f, Y1h, Xtf, NT, D, NT, 2 * NT);

    // 7. h = relu(Y1 @ mlp_in).
    gemm_narrow<3, false, false><<<dim3(D / 64, NT / BM), 256, 0, stream>>>(
        Y1h, W4t, nullptr, hb, nullptr, NT, D, D, D);

    // 8. out = (Y1 + h @ mlp_out)^T.
    gemm_narrow<4, false, false><<<dim3(D / 64, NT / BM), 256, 0, stream>>>(
        hb, W5t, outF, nullptr, Y1f, NT, D, D, D);
}

// Round 8
// 287.789 us; speedup vs baseline: 1.8363x; 1.0181x over previous
//
#include <hip/hip_runtime.h>
#include <stdint.h>
#include <stddef.h>

using f16 = _Float16;
typedef __attribute__((ext_vector_type(8))) _Float16 f16x8;
typedef __attribute__((ext_vector_type(4))) float f32x4;

constexpr int BM = 128, BN = 128;

// ---------------------------------------------------------------------------
__device__ __forceinline__ void async_copy16(const f16* g, f16* l) {
    __builtin_amdgcn_global_load_lds(
        (const __attribute__((address_space(1))) void*)g,
        (__attribute__((address_space(3))) void*)l, 16, 0, 0);
}

// ---------------------------------------------------------------------------
// Transpose X [D][NT] fp32 -> Xt [NT][D] fp32 + fp16.
__global__ __launch_bounds__(256)
void transpose_x(const float* __restrict__ in, float* __restrict__ outF,
                 f16* __restrict__ outH, int R, int C) {
    __shared__ float tile[32][33];
    const int tx = threadIdx.x & 31, ty = threadIdx.x >> 5;
    const int c0 = blockIdx.x * 32, r0 = blockIdx.y * 32;
#pragma unroll
    for (int j = 0; j < 4; j++)
        tile[ty + j * 8][tx] = in[(size_t)(r0 + ty + j * 8) * C + c0 + tx];
    __syncthreads();
#pragma unroll
    for (int j = 0; j < 4; j++) {
        float v = tile[tx][ty + j * 8];
        size_t idx = (size_t)(c0 + ty + j * 8) * R + r0 + tx;
        outF[idx] = v;
        outH[idx] = (f16)v;
    }
}

// Weight prep: z<3 -> fp16 convert (Wq, Wk, Wv); z>=3 -> fp16 transpose.
__global__ __launch_bounds__(256)
void prep_w(const float* __restrict__ w0, const float* __restrict__ w1,
            const float* __restrict__ w2, const float* __restrict__ w3,
            const float* __restrict__ w4, const float* __restrict__ w5,
            f16* o0, f16* o1, f16* o2, f16* o3, f16* o4, f16* o5, int D) {
    const int z = blockIdx.z;
    const float* in = z == 0 ? w0 : z == 1 ? w1 : z == 2 ? w2 : z == 3 ? w3 : z == 4 ? w4 : w5;
    f16* out = z == 0 ? o0 : z == 1 ? o1 : z == 2 ? o2 : z == 3 ? o3 : z == 4 ? o4 : o5;
    const int tx = threadIdx.x & 31, ty = threadIdx.x >> 5;
    const int c0 = blockIdx.x * 32, r0 = blockIdx.y * 32;
    if (z < 3) {
#pragma unroll
        for (int j = 0; j < 4; j++) {
            size_t idx = (size_t)(r0 + ty + j * 8) * D + c0 + tx;
            out[idx] = (f16)in[idx];
        }
    } else {
        __shared__ float tile[32][33];
#pragma unroll
        for (int j = 0; j < 4; j++)
            tile[ty + j * 8][tx] = in[(size_t)(r0 + ty + j * 8) * D + c0 + tx];
        __syncthreads();
#pragma unroll
        for (int j = 0; j < 4; j++)
            out[(size_t)(c0 + ty + j * 8) * D + r0 + tx] = (f16)tile[tx][ty + j * 8];
    }
}

// ---------------------------------------------------------------------------
// Causal softmax IN-PLACE: fp32 S row -> fp16 A in same memory (pitch 2N).
// Full-row writes (R6 semantics — zeros through col N-1).
__global__ __launch_bounds__(256)
void softmax_causal_inplace(float* __restrict__ S, int N) {
    const int row = blockIdx.x;
    const int len = row + 1;
    float* s = S + (size_t)row * N;
    f16* a = (f16*)s;
    __shared__ float red[256];
    const int t = threadIdx.x;

    float v[16];
    float mx = -1e30f;
#pragma unroll
    for (int j = 0; j < 16; j++) {
        int c = t + j * 256;
        if (c < len) { v[j] = s[c]; mx = fmaxf(mx, v[j]); }
    }
    red[t] = mx; __syncthreads();
    for (int o = 128; o > 0; o >>= 1) { if (t < o) red[t] = fmaxf(red[t], red[t + o]); __syncthreads(); }
    mx = red[0]; __syncthreads();

    float sum = 0.f;
#pragma unroll
    for (int j = 0; j < 16; j++) {
        int c = t + j * 256;
        if (c < len) sum += __expf(v[j] - mx);
    }
    red[t] = sum; __syncthreads();
    for (int o = 128; o > 0; o >>= 1) { if (t < o) red[t] += red[t + o]; __syncthreads(); }
    const float inv = 1.0f / red[0];
#pragma unroll
    for (int j = 0; j < 16; j++) {
        int c = t + j * 256;
        a[c] = (f16)((c < len) ? __expf(v[j] - mx) * inv : 0.0f);
    }
}

// ---------------------------------------------------------------------------
// 128x128x64 fp16 GEMM body, R6-proven global_load_lds staging.
// LDS per operand: [2 k-halves][128][32].
// MODE 0: Ch = f16(acc);  MODE 1: Cf = acc.
template <int MODE>
__device__ __forceinline__ void plain_body(
    f16* lA, f16* lB, const f16* __restrict__ A, const f16* __restrict__ B,
    float* __restrict__ Cf, f16* __restrict__ Ch,
    int m0, int n0, int N, int K, int lda) {
    const int t = threadIdx.x;
    const int lane = t & 63, wave = t >> 6;
    const int wm = (wave >> 1) * 64, wn = (wave & 1) * 64;
    const int lm = lane & 15, lq = lane >> 4;
    const int sr = t >> 2, sc = (t & 3) * 8;

    f32x4 acc[4][4] = {};

    for (int k0 = 0; k0 < K; k0 += 64) {
#pragma unroll
        for (int r = 0; r < 4; r++) {
            const int row = sr + (r & 1) * 64;
            const int col = k0 + (r >> 1) * 32 + sc;
            async_copy16(A + (size_t)(m0 + row) * lda + col, lA + r * 2048 + t * 8);
        }
#pragma unroll
        for (int r = 0; r < 4; r++) {
            const int row = sr + (r & 1) * 64;
            const int col = k0 + (r >> 1) * 32 + sc;
            async_copy16(B + (size_t)(n0 + row) * K + col, lB + r * 2048 + t * 8);
        }
        __syncthreads();

#pragma unroll
        for (int kk = 0; kk < 2; kk++) {
            f16x8 af[4], bfr[4];
#pragma unroll
            for (int i = 0; i < 4; i++)
                af[i] = *(const f16x8*)&lA[kk * 4096 + (wm + i * 16 + lm) * 32 + lq * 8];
#pragma unroll
            for (int j = 0; j < 4; j++)
                bfr[j] = *(const f16x8*)&lB[kk * 4096 + (wn + j * 16 + lm) * 32 + lq * 8];
#pragma unroll
            for (int i = 0; i < 4; i++)
#pragma unroll
                for (int j = 0; j < 4; j++)
                    acc[i][j] = __builtin_amdgcn_mfma_f32_16x16x32_f16(
                        af[i], bfr[j], acc[i][j], 0, 0, 0);
        }
        __syncthreads();
    }

    // C/D layout: col = lane&15, row = (lane>>4)*4 + reg.
#pragma unroll
    for (int i = 0; i < 4; i++) {
        const int row = m0 + wm + i * 16 + lq * 4;
#pragma unroll
        for (int j = 0; j < 4; j++) {
            const int col = n0 + wn + j * 16 + lm;
            f32x4 v = acc[i][j];
#pragma unroll
            for (int r = 0; r < 4; r++) {
                if (MODE == 0) Ch[(size_t)(row + r) * N + col] = (f16)v[r];
                else           Cf[(size_t)(row + r) * N + col] = v[r];
            }
        }
    }
}

// ---------------------------------------------------------------------------
// 128x64x64 fp16 GEMM body, R6-proven staging. 4 waves stacked on M.
// A: [2][128][32] in 4 rounds; B: [2][64][32] in 2 rounds (all 256 threads).
// MODE 2: Cf = acc + resid; Ch = f16(Cf)
// MODE 3: Ch = f16(relu(acc))
// MODE 4: Cf[col*M + row] = acc + resid[row*N + col]   (transposed store)
template <int MODE>
__device__ __forceinline__ void narrow_body(
    f16* lA, f16* lB, const f16* __restrict__ A, const f16* __restrict__ B,
    float* __restrict__ Cf, f16* __restrict__ Ch, const float* __restrict__ resid,
    int m0, int n0, int M, int N, int K, int lda, int Keff) {
    const int t = threadIdx.x;
    const int lane = t & 63, wave = t >> 6;
    const int lm = lane & 15, lq = lane >> 4;
    const int sr = t >> 2, sc = (t & 3) * 8;

    f32x4 acc[2][4] = {};

    for (int k0 = 0; k0 < Keff; k0 += 64) {
#pragma unroll
        for (int r = 0; r < 4; r++) {
            const int row = sr + (r & 1) * 64;
            const int col = k0 + (r >> 1) * 32 + sc;
            async_copy16(A + (size_t)(m0 + row) * lda + col, lA + r * 2048 + t * 8);
        }
#pragma unroll
        for (int r = 0; r < 2; r++) {
            const int col = k0 + r * 32 + sc;
            async_copy16(B + (size_t)(n0 + sr) * K + col, lB + r * 2048 + t * 8);
        }
        __syncthreads();

#pragma unroll
        for (int kk = 0; kk < 2; kk++) {
            f16x8 af[2], bfr[4];
#pragma unroll
            for (int i = 0; i < 2; i++)
                af[i] = *(const f16x8*)&lA[kk * 4096 + (wave * 32 + i * 16 + lm) * 32 + lq * 8];
#pragma unroll
            for (int j = 0; j < 4; j++)
                bfr[j] = *(const f16x8*)&lB[kk * 2048 + (j * 16 + lm) * 32 + lq * 8];
#pragma unroll
            for (int i = 0; i < 2; i++)
#pragma unroll
                for (int j = 0; j < 4; j++)
                    acc[i][j] = __builtin_amdgcn_mfma_f32_16x16x32_f16(
                        af[i], bfr[j], acc[i][j], 0, 0, 0);
        }
        __syncthreads();
    }

#pragma unroll
    for (int i = 0; i < 2; i++) {
        const int row = m0 + wave * 32 + i * 16 + lq * 4;
#pragma unroll
        for (int j = 0; j < 4; j++) {
            const int col = n0 + j * 16 + lm;
            f32x4 v = acc[i][j];
#pragma unroll
            for (int r = 0; r < 4; r++) {
                if (MODE == 2) {
                    float o = v[r] + resid[(size_t)(row + r) * N + col];
                    Cf[(size_t)(row + r) * N + col] = o;
                    Ch[(size_t)(row + r) * N + col] = (f16)o;
                } else if (MODE == 3) {
                    Ch[(size_t)(row + r) * N + col] = (f16)fmaxf(v[r], 0.0f);
                } else {
                    float o = v[r] + resid[(size_t)(row + r) * N + col];
                    Cf[(size_t)col * M + (row + r)] = o;
                }
            }
        }
    }
}

// ---------------------------------------------------------------------------
// Fused: GT = Wk*Wq^T ++ HT = Wo^T*Wv^T, both [1024^3], 128 blocks.
__global__ __launch_bounds__(256)
void tiny_pair(const f16* Wkh, const f16* Wqh, f16* GT,
               const f16* Wot, const f16* Wvh, f16* HT) {
    __shared__ alignas(16) f16 smem[2 * 8192];
    const int x = blockIdx.x;
    if (x < 64) {
        plain_body<0>(smem, smem + 8192, Wkh, Wqh, nullptr, GT,
                      (x >> 3) * BM, (x & 7) * BN, 1024, 1024, 1024);
    } else {
        const int r = x - 64;
        plain_body<0>(smem, smem + 8192, Wot, Wvh, nullptr, HT,
                      (r >> 3) * BM, (r & 7) * BN, 1024, 1024, 1024);
    }
}

// Fused: Q' = Xt*GT^T [4096,1024,1024] ++ RHt = HT*Xt^T [1024,4096,1024].
// XCD-affinity: blocks sharing an Xt stripe land on one blockIdx%8 residue.
__global__ __launch_bounds__(256)
void mid_pair(const f16* Xth, const f16* GT, f16* Qp,
              const f16* HT, f16* RHt) {
    __shared__ alignas(16) f16 smem[2 * 8192];
    const int b = blockIdx.x;
    const int x = b & 7;
    if (b < 256) {
        const int s = b >> 3;  // 0..31
        const int m = x + 8 * (s >> 3), n = s & 7;
        plain_body<0>(smem, smem + 8192, Xth, GT, nullptr, Qp,
                      m * BM, n * BN, 1024, 1024, 1024);
    } else {
        const int s = (b - 256) >> 3;  // 0..31
        const int n = x + 8 * (s >> 3), m = s & 7;
        plain_body<0>(smem, smem + 8192, HT, Xth, nullptr, RHt,
                      m * BM, n * BN, 4096, 1024, 1024);
    }
}

// Scores over lower triangle: S = Q'*Xt^T, fp32 out, 528 blocks.
// XCD-affinity + balance: residue x owns m in {31-x, 16+x, 15-x, x}
// (66 blocks per residue, long-K first).
__global__ __launch_bounds__(256)
void scores_tri(const f16* Qp, const f16* Xth, float* S) {
    __shared__ alignas(16) f16 smem[2 * 8192];
    const int x = blockIdx.x & 7, s = blockIdx.x >> 3;  // s in 0..65
    const int c0 = 32 - x, c1 = 17 + x, c2 = 16 - x;
    int m, n;
    if (s < c0)                { m = 31 - x; n = s; }
    else if (s < c0 + c1)      { m = 16 + x; n = s - c0; }
    else if (s < c0 + c1 + c2) { m = 15 - x; n = s - c0 - c1; }
    else                       { m = x;      n = s - c0 - c1 - c2; }
    plain_body<1>(smem, smem + 8192, Qp, Xth, S, nullptr,
                  m * BM, n * BN, 4096, 1024, 1024);
}

// Standalone narrow GEMM, 1D grid of 512 (M=4096, N=1024).
// SWZ 0: uniform-K, residue x owns m = x + 8*(s>>4).
// SWZ 1: causal-K balanced, residue x owns m in {31-x, 16+x, 15-x, x}.
template <int MODE, bool CAUSAL_K, int SWZ>
__global__ __launch_bounds__(256)
void gemm_narrow(const f16* __restrict__ A, const f16* __restrict__ B,
                 float* __restrict__ Cf, f16* __restrict__ Ch,
                 const float* __restrict__ resid, int M, int N, int K, int lda) {
    __shared__ alignas(16) f16 smem[8192 + 4096];
    const int x = blockIdx.x & 7, s = blockIdx.x >> 3;  // s in 0..63
    const int q = s >> 4, n = s & 15;
    int m;
    if (SWZ == 1) m = (q == 0) ? 31 - x : (q == 1) ? 16 + x : (q == 2) ? 15 - x : x;
    else          m = x + 8 * q;
    const int m0 = m * BM, n0 = n * 64;
    const int Keff = CAUSAL_K ? (K < m0 + BM ? K : m0 + BM) : K;
    narrow_body<MODE>(smem, smem + 8192, A, B, Cf, Ch, resid,
                      m0, n0, M, N, K, lda, Keff);
}

// ---------------------------------------------------------------------------
extern "C" void kernel_launch(void* const* d_in, const int* in_sizes, int n_in,
                              void* d_out, int out_size, void* d_ws, size_t ws_size,
                              hipStream_t stream) {
    const int D = 1024, NT = 4096;
    const float* X = (const float*)d_in[0];
    const float* W[6] = {(const float*)d_in[1], (const float*)d_in[2],
                         (const float*)d_in[3], (const float*)d_in[4],
                         (const float*)d_in[5], (const float*)d_in[6]};
    char* ws = (char*)d_ws;
    auto MB = [](size_t x) { return x << 20; };

    // Workspace (144 MB peak):
    float* Xtf  = (float*)(ws + MB(0));    // [NT][D] fp32 residual
    f16*   Xth  = (f16*)(ws + MB(16));     // [NT][D]
    f16*   Wqh  = (f16*)(ws + MB(24));
    f16*   Wkh  = (f16*)(ws + MB(26));
    f16*   Wvh  = (f16*)(ws + MB(28));
    f16*   Wot  = (f16*)(ws + MB(30));
    f16*   W4t  = (f16*)(ws + MB(32));
    f16*   W5t  = (f16*)(ws + MB(34));
    f16*   GT   = (f16*)(ws + MB(36));     // [D][D]
    f16*   HT   = (f16*)(ws + MB(38));     // [D][D]
    f16*   Qp   = (f16*)(ws + MB(40));     // [NT][D] (dead after scores)
    float* S    = (float*)(ws + MB(48));   // [NT][NT] fp32 -> A f16 in-place
    f16*   RHt  = (f16*)(ws + MB(112));    // [D][NT]
    float* Y1f  = (float*)(ws + MB(120));  // [NT][D] fp32
    f16*   Y1h  = (f16*)(ws + MB(136));    // [NT][D]
    f16*   hb   = (f16*)(ws + MB(40));     // over Qp (dead)
    float* outF = (float*)d_out;           // [D][NT]

    // 1. Prep.
    transpose_x<<<dim3(NT / 32, D / 32), 256, 0, stream>>>(X, Xtf, Xth, D, NT);
    prep_w<<<dim3(D / 32, D / 32, 6), 256, 0, stream>>>(
        W[0], W[1], W[2], W[3], W[4], W[5], Wqh, Wkh, Wvh, Wot, W4t, W5t, D);

    // 2. GT = Wk*Wq^T ++ HT = Wo^T*Wv^T.
    tiny_pair<<<128, 256, 0, stream>>>(Wkh, Wqh, GT, Wot, Wvh, HT);

    // 3. Q' = Xt*G ++ RHt = HT*Xt^T.
    mid_pair<<<512, 256, 0, stream>>>(Xth, GT, Qp, HT, RHt);

    // 4. Scores (lower triangle, fp32).
    scores_tri<<<528, 256, 0, stream>>>(Qp, Xth, S);

    // 5. Softmax in-place (A f16, pitch 2*NT).
    softmax_causal_inplace<<<NT, 256, 0, stream>>>(S, NT);
    f16* Ab = (f16*)S;

    // 6. Y1 = Xt + A@RH (causal-K truncation, XCD-affine + balanced).
    gemm_narrow<2, true, 1><<<512, 256, 0, stream>>>(
        Ab, RHt, Y1f, Y1h, Xtf, NT, D, NT, 2 * NT);

    // 7. h = relu(Y1 @ mlp_in).
    gemm_narrow<3, false, 0><<<512, 256, 0, stream>>>(
        Y1h, W4t, nullptr, hb, nullptr, NT, D, D, D);

    // 8. out = (Y1 + h @ mlp_out)^T.
    gemm_narrow<4, false, 0><<<512, 256, 0, stream>>>(
        hb, W5t, outF, nullptr, Y1f, NT, D, D, D);
}